// Round 12
// baseline (209.402 us; speedup 1.0000x reference)
//
#include <hip/hip_runtime.h>

#define NB 16384
#define NDOM 10
#define HIDN 512
#define STYLE 64
#define NWIN 512   // NB / 32

typedef short bf16x8 __attribute__((ext_vector_type(8)));
typedef float f32x16 __attribute__((ext_vector_type(16)));

#define MFMA __builtin_amdgcn_mfma_f32_32x32x16_bf16

// ---------------- bf16 helpers ----------------

__device__ __forceinline__ unsigned bfr_hi(float x) {
    unsigned u = __float_as_uint(x);
    return (u + 0x7fffu + ((u >> 16) & 1u)) & 0xffff0000u;  // RNE bf16 in high bits
}

__device__ __forceinline__ unsigned cvtpk(float a, float b) {
    unsigned r;
    asm("v_cvt_pk_bf16_f32 %0, %1, %2" : "=v"(r) : "v"(a), "v"(b));
    return r;   // [15:0]=bf16(a), [31:16]=bf16(b)
}

__device__ __forceinline__ void cvhalf2(const float4& x, const float4& y, uint4& h, uint4& l) {
    float xs[8] = {x.x, x.y, x.z, x.w, y.x, y.y, y.z, y.w};
    unsigned hh[8], ll[8];
#pragma unroll
    for (int i = 0; i < 8; ++i) {
        unsigned hb = bfr_hi(xs[i]);
        hh[i] = hb;
        ll[i] = bfr_hi(xs[i] - __uint_as_float(hb));
    }
    h = make_uint4((hh[0] >> 16) | (hh[1] & 0xffff0000u), (hh[2] >> 16) | (hh[3] & 0xffff0000u),
                   (hh[4] >> 16) | (hh[5] & 0xffff0000u), (hh[6] >> 16) | (hh[7] & 0xffff0000u));
    l = make_uint4((ll[0] >> 16) | (ll[1] & 0xffff0000u), (ll[2] >> 16) | (ll[3] & 0xffff0000u),
                   (ll[4] >> 16) | (ll[5] & 0xffff0000u), (ll[6] >> 16) | (ll[7] & 0xffff0000u));
}

// ---------------- scatter (parallel, 64 blocks) ------
// Placement within a domain is atomic-order dependent, but every row's output
// value is position-independent -> d_out deterministic.

__global__ void k_scatter(const int* __restrict__ y, const int* __restrict__ counts,
                          int* __restrict__ cursors, int* __restrict__ rowidx) {
    __shared__ int soff[NDOM];
    if (threadIdx.x == 0) {
        int s = 0;
        for (int dd = 0; dd < NDOM; ++dd) { soff[dd] = s; s += counts[dd]; }
    }
    __syncthreads();
    int b = blockIdx.x * 256 + threadIdx.x;   // grid 64
    int d = y[b];
    int lane = threadIdx.x & 63;
#pragma unroll
    for (int dd = 0; dd < NDOM; ++dd) {
        unsigned long long bal = __ballot(d == dd);
        if (bal == 0ULL) continue;
        int leader = __builtin_ctzll(bal);
        int base = 0;
        if (d == dd && lane == leader)
            base = atomicAdd(&cursors[dd], (int)__popcll(bal));
        base = __shfl(base, leader);
        if (d == dd) {
            int rank = (int)__popcll(bal & ((1ULL << lane) - 1ULL));
            rowidx[soff[dd] + base + rank] = b;
        }
    }
}

// ---------------- weight prep + histogram (single kernel) ------------------
// Big mats (512x512): per (mat, wq) block of 32768 shorts:
//   addr = ks*1024 + of*512 + k8*256 + c5*8 + j ; k = ks*16+k8*8+j, col = wq*64+of*32+c5
// mats: 0..2 = W1..W3 ; 3+d = Wu1[d] ; 13+d = Wu2[d] ; 23+d = Wu3[d]
// W0 (16x512): granule g: wq=g>>7, of=(g>>6)&1, k8=(g>>5)&1, c5=g&31 at W0p+g*8
// Wo (per dom 512x64): granule g: w1=g>>11, ks=(g>>6)&31, k8=(g>>5)&1, c5=g&31
// grid: 1056 big-mat + 1 W0 + 10 Wo + 64 hist = 1131

__global__ void k_prep(const float* __restrict__ W1, const float* __restrict__ W2,
                       const float* __restrict__ W3, const float* __restrict__ Wu1,
                       const float* __restrict__ Wu2, const float* __restrict__ Wu3,
                       const float* __restrict__ W0, const float* __restrict__ Wo,
                       const int* __restrict__ y,
                       short* __restrict__ Wp, short* __restrict__ W0p,
                       short* __restrict__ WoP, int* __restrict__ counts)
{
    const int b = blockIdx.x;
    const int t = threadIdx.x;
    if (b < 1056) {
        __shared__ float Ld[64][66];
        const int mat = b >> 5, wq = (b >> 2) & 7, sh = b & 3;
        const float* src;
        if (mat < 3) src = (mat == 0 ? W1 : (mat == 1 ? W2 : W3));
        else {
            int g = (mat - 3) / 10, d = (mat - 3) % 10;
            src = (g == 0 ? Wu1 : (g == 1 ? Wu2 : Wu3)) + (size_t)d * HIDN * HIDN;
        }
        short* dst = Wp + (size_t)mat * 262144 + wq * 32768;
        for (int s = sh * 2; s < sh * 2 + 2; ++s) {
            __syncthreads();
            const int r4 = t >> 6, c = t & 63;
#pragma unroll
            for (int p = 0; p < 16; ++p) {
                int k = s * 64 + p * 4 + r4;
                Ld[p * 4 + r4][c] = src[(size_t)k * HIDN + wq * 64 + c];
            }
            __syncthreads();
#pragma unroll
            for (int i = 0; i < 2; ++i) {
                int g = i * 256 + t;
                int ksl = g >> 7, of = (g >> 6) & 1, k8 = (g >> 5) & 1, c5 = g & 31;
                int kk = ksl * 16 + k8 * 8;
                unsigned pk[4];
#pragma unroll
                for (int j2 = 0; j2 < 4; ++j2) {
                    unsigned h0 = bfr_hi(Ld[kk + 2 * j2][of * 32 + c5]);
                    unsigned h1 = bfr_hi(Ld[kk + 2 * j2 + 1][of * 32 + c5]);
                    pk[j2] = (h0 >> 16) | (h1 & 0xffff0000u);
                }
                int ksg = s * 4 + ksl;
                *(uint4*)(dst + ksg * 1024 + of * 512 + k8 * 256 + c5 * 8) =
                    make_uint4(pk[0], pk[1], pk[2], pk[3]);
            }
        }
    } else if (b == 1056) {
#pragma unroll
        for (int i = 0; i < 4; ++i) {
            int g = i * 256 + t;   // 1024 granules
            int wq = g >> 7, of = (g >> 6) & 1, k8 = (g >> 5) & 1, c5 = g & 31;
            int col = wq * 64 + of * 32 + c5;
            unsigned pk[4];
#pragma unroll
            for (int j2 = 0; j2 < 4; ++j2) {
                unsigned h0 = bfr_hi(W0[(size_t)(k8 * 8 + 2 * j2) * HIDN + col]);
                unsigned h1 = bfr_hi(W0[(size_t)(k8 * 8 + 2 * j2 + 1) * HIDN + col]);
                pk[j2] = (h0 >> 16) | (h1 & 0xffff0000u);
            }
            *(uint4*)(W0p + g * 8) = make_uint4(pk[0], pk[1], pk[2], pk[3]);
        }
    } else if (b < 1067) {
        const int dom = b - 1057;
        const float* src = Wo + (size_t)dom * HIDN * STYLE;
        short* dst = WoP + (size_t)dom * 32768;
#pragma unroll
        for (int i = 0; i < 16; ++i) {
            int g = i * 256 + t;   // 4096 granules
            int w1 = g >> 11, ks = (g >> 6) & 31, k8 = (g >> 5) & 1, c5 = g & 31;
            int col = w1 * 32 + c5;
            int k0 = ks * 16 + k8 * 8;
            unsigned pk[4];
#pragma unroll
            for (int j2 = 0; j2 < 4; ++j2) {
                unsigned h0 = bfr_hi(src[(size_t)(k0 + 2 * j2) * STYLE + col]);
                unsigned h1 = bfr_hi(src[(size_t)(k0 + 2 * j2 + 1) * STYLE + col]);
                pk[j2] = (h0 >> 16) | (h1 & 0xffff0000u);
            }
            *(uint4*)(dst + g * 8) = make_uint4(pk[0], pk[1], pk[2], pk[3]);
        }
    } else {
        // ---- domain histogram (64 blocks' worth folded in) ----
        int idx = (b - 1067) * 256 + t;
        int d = y[idx];
        int lane = t & 63;
#pragma unroll
        for (int dd = 0; dd < NDOM; ++dd) {
            unsigned long long bal = __ballot(d == dd);
            if (bal != 0ULL && d == dd && lane == __builtin_ctzll(bal))
                atomicAdd(&counts[dd], (int)__popcll(bal));
        }
    }
}

// ---------------- fused persistent kernel ----------------
// 512 blocks x 1024 threads (16 waves), block = 32 sorted rows; 64.5 KB LDS
// -> 2 blocks/CU => 32 waves/CU = 8 waves/SIMD (HW max; rounds 10->11 proved
// waves/SIMD is the binding lever: 2w=164us, 4w=127us).
// Wave w (0..15) owns outcols [32w,32w+32) (of gone) -> ~60 regs/wave, fits
// the 64-VGPR budget 8 waves/SIMD requires (launch_bounds(1024,8)).
// h in LDS: octet o=k>>3, line = o*256 + row*8 shorts, 16B/line.
// Operand-swapped MFMA: A = weights (m=outcol), B = activations (n=batchrow).
// Weight ring depth 4; h-frags 1 ks ahead. hi+lo into ONE chain (16 acc regs);
// dep latency covered by 8-way TLP. Per-output sum order == round 11.

template<bool BLO>
__device__ __forceinline__ void pass512(const short* __restrict__ sH,
                                        const short* __restrict__ sL,
                                        const short* __restrict__ pW,
                                        int w, int lane, f32x16& acc)
{
#pragma unroll
    for (int e = 0; e < 16; ++e) acc[e] = 0.f;
    const int rb = (lane & 31) * 8;
    const int lh = lane >> 5;
    const short* p = pW + (w >> 1) * 32768 + (w & 1) * 512 + lane * 8;
    // weight ring, depth 4 (4 dwordx4 loads in flight)
    bf16x8 wv[4];
#pragma unroll
    for (int d = 0; d < 4; ++d) wv[d] = *(const bf16x8*)(p + d * 1024);
    // h-frag double buffer (read 1 ks ahead)
    bf16x8 hb[2], lb[2];
    hb[0] = *(const bf16x8*)(sH + lh * 256 + rb);
    if (BLO) lb[0] = *(const bf16x8*)(sL + lh * 256 + rb);
#pragma unroll
    for (int ks = 0; ks < 32; ++ks) {
        const int pc = ks & 1, pn = pc ^ 1;
        bf16x8 wk = wv[ks & 3];
        if (ks < 28) wv[ks & 3] = *(const bf16x8*)(p + (ks + 4) * 1024);
        if (ks < 31) {
            const int basen = (2 * (ks + 1) + lh) * 256 + rb;
            hb[pn] = *(const bf16x8*)(sH + basen);
            if (BLO) lb[pn] = *(const bf16x8*)(sL + basen);
        }
        acc = MFMA(wk, hb[pc], acc, 0, 0, 0);
        if (BLO) acc = MFMA(wk, lb[pc], acc, 0, 0, 0);
    }
}

// epilogue: bias (+ReLU), pack bf16 hi(/lo), shuffle-repack so each half-wave
// writes full contiguous 16B lines (conflict-free ds_write_b128).
template<bool WLO, bool RELU>
__device__ __forceinline__ void epi512(short* __restrict__ sH, short* __restrict__ sL,
                                       f32x16& acc,
                                       const float* __restrict__ bias,
                                       int w, int lane, int rlo, int rhi)
{
    const int lh = lane >> 5;
    const int row = lane & 31;
    const bool pred = (row >= rlo && row < rhi);
    unsigned mh[4][2], ml[4][2];
#pragma unroll
    for (int q = 0; q < 4; ++q) {
        // my 4 k-values: k = w*32 + q*8 + lh*4 + j
        const float4 bv = *(const float4*)&bias[w * 32 + q * 8 + lh * 4];
        float v[4];
#pragma unroll
        for (int j = 0; j < 4; ++j) {
            float x = acc[q * 4 + j] + (&bv.x)[j];
            if (RELU) x = fmaxf(x, 0.f);
            v[j] = x;
        }
        mh[q][0] = cvtpk(v[0], v[1]);
        mh[q][1] = cvtpk(v[2], v[3]);
        if (WLO) {
            float l0 = v[0] - __uint_as_float(mh[q][0] << 16);
            float l1 = v[1] - __uint_as_float(mh[q][0] & 0xffff0000u);
            float l2 = v[2] - __uint_as_float(mh[q][1] << 16);
            float l3 = v[3] - __uint_as_float(mh[q][1] & 0xffff0000u);
            ml[q][0] = cvtpk(l0, l1);
            ml[q][1] = cvtpk(l2, l3);
        }
    }
    // exchange with lane^32 (same row, other half of each 16B line);
    // lane writes full lines for q = 2t + lh -> contiguous per half-wave
#pragma unroll
    for (int t = 0; t < 2; ++t) {
        const int q = 2 * t + lh;
        const int qs = 2 * t + (lh ^ 1);
        unsigned r0 = (unsigned)__shfl_xor((int)mh[qs][0], 32);
        unsigned r1 = (unsigned)__shfl_xor((int)mh[qs][1], 32);
        uint4 line = lh == 0 ? make_uint4(mh[q][0], mh[q][1], r0, r1)
                             : make_uint4(r0, r1, mh[q][0], mh[q][1]);
        const int o = w * 4 + q;
        if (pred) *(uint4*)(sH + o * 256 + row * 8) = line;
        if (WLO) {
            unsigned s0 = (unsigned)__shfl_xor((int)ml[qs][0], 32);
            unsigned s1 = (unsigned)__shfl_xor((int)ml[qs][1], 32);
            uint4 lin2 = lh == 0 ? make_uint4(ml[q][0], ml[q][1], s0, s1)
                                 : make_uint4(s0, s1, ml[q][0], ml[q][1]);
            if (pred) *(uint4*)(sL + o * 256 + row * 8) = lin2;
        }
    }
}

__global__ __launch_bounds__(1024, 8)
void k_fused(const float* __restrict__ z, const int* __restrict__ rowidx,
             const int* __restrict__ counts,
             const short* __restrict__ Wp, const short* __restrict__ W0p,
             const short* __restrict__ WoP,
             const float* __restrict__ b0, const float* __restrict__ b1,
             const float* __restrict__ b2, const float* __restrict__ b3,
             const float* __restrict__ bu1, const float* __restrict__ bu2,
             const float* __restrict__ bu3, const float* __restrict__ bo,
             float* __restrict__ out)
{
    __shared__ short sH[16384];   // 32 KiB  (h hi)
    __shared__ short sL[16384];   // 32 KiB  (h lo; valid from layer-3 output on)
    __shared__ int soff[NDOM + 1];

    // XCD-chunked bijective swizzle: neighbors share a domain -> L2 reuse
    const int win = (blockIdx.x & 7) * 64 + (blockIdx.x >> 3);
    const int row0 = win * 32;
    const int tid = threadIdx.x;
    const int lane = tid & 63;
    const int w = tid >> 6;      // 0..15
    const int lh = lane >> 5;

    if (tid == 0) {
        int s = 0;
#pragma unroll
        for (int dd = 0; dd < NDOM; ++dd) { soff[dd] = s; s += counts[dd]; }
        soff[NDOM] = s;
    }
    // soff first read in the head loop — multiple __syncthreads before then

    f32x16 acc;

    // ---- layer 0: z (K=16) -> h (hi-only out; z itself split hi/lo) ----
    {
#pragma unroll
        for (int e = 0; e < 16; ++e) acc[e] = 0.f;
        bf16x8 w0v = *(const bf16x8*)(W0p + (w >> 1) * 1024 + (w & 1) * 512 + lane * 8);
        const int r = lane & 31;
        const int src = rowidx[row0 + r];
        const float* zp = z + (size_t)src * 16 + lh * 8;
        float4 f0 = *(const float4*)zp;
        float4 f1 = *(const float4*)(zp + 4);
        uint4 h, l;
        cvhalf2(f0, f1, h, l);
        bf16x8 zh = *(bf16x8*)&h;
        bf16x8 zl = *(bf16x8*)&l;
        acc = MFMA(w0v, zh, acc, 0, 0, 0);
        acc = MFMA(w0v, zl, acc, 0, 0, 0);
        epi512<false, true>(sH, sL, acc, b0, w, lane, 0, 32);
        __syncthreads();
    }

    // ---- trunk layers 1-3 (h hi-only inputs; layer 3 writes hi+lo) ----
#pragma unroll 1
    for (int m = 0; m < 3; ++m) {
        const float* bp = (m == 0) ? b1 : (m == 1) ? b2 : b3;
        pass512<false>(sH, sL, Wp + (size_t)m * 262144, w, lane, acc);
        __syncthreads();
        if (m < 2) epi512<false, true>(sH, sL, acc, bp, w, lane, 0, 32);
        else       epi512<true,  true>(sH, sL, acc, bp, w, lane, 0, 32);
        __syncthreads();
    }

    // ---- head layers: per-domain segments (predicated epilogue rows) ----
#pragma unroll 1
    for (int L = 0; L < 3; ++L) {
        const short* WL_ = Wp + (size_t)(3 + L * 10) * 262144;
        const float* bL = (L == 0) ? bu1 : (L == 1) ? bu2 : bu3;
#pragma unroll 1
        for (int d = 0; d < NDOM; ++d) {
            int rlo = soff[d] - row0, rhi = soff[d + 1] - row0;
            rlo = rlo < 0 ? 0 : rlo;
            rhi = rhi > 32 ? 32 : rhi;
            if (rhi <= rlo) continue;
            pass512<true>(sH, sL, WL_ + (size_t)d * 262144, w, lane, acc);
            __syncthreads();
            epi512<true, true>(sH, sL, acc, bL + d * HIDN, w, lane, rlo, rhi);
            __syncthreads();
        }
    }

    // ---- final 512->64: waves 0-1, wave = 32 outcols; coalesced float4 out ----
    if (w < 2) {
        const int r = lane & 31;
#pragma unroll 1
        for (int d = 0; d < NDOM; ++d) {
            int rlo = soff[d] - row0, rhi = soff[d + 1] - row0;
            rlo = rlo < 0 ? 0 : rlo;
            rhi = rhi > 32 ? 32 : rhi;
            if (rhi <= rlo) continue;
            f32x16 fh, fl;   // split chains here (single chain/wave otherwise)
#pragma unroll
            for (int e = 0; e < 16; ++e) { fh[e] = 0.f; fl[e] = 0.f; }
            const short* pw = WoP + (size_t)d * 32768 + w * 16384 + lane * 8;
            bf16x8 wb[4];
#pragma unroll
            for (int dd = 0; dd < 4; ++dd) wb[dd] = *(const bf16x8*)(pw + dd * 512);
#pragma unroll
            for (int ks = 0; ks < 32; ++ks) {
                bf16x8 wk = wb[ks & 3];
                if (ks < 28) wb[ks & 3] = *(const bf16x8*)(pw + (ks + 4) * 512);
                const int base = (2 * ks + lh) * 256 + (lane & 31) * 8;
                bf16x8 bhv = *(const bf16x8*)(sH + base);
                bf16x8 blv = *(const bf16x8*)(sL + base);
                fh = MFMA(wk, bhv, fh, 0, 0, 0);
                fl = MFMA(wk, blv, fl, 0, 0, 0);
            }
            if (r >= rlo && r < rhi) {
                const int orow = rowidx[row0 + r];
                float* op = out + (size_t)orow * STYLE + w * 32 + lh * 4;
                const float* bop = bo + d * STYLE + w * 32 + lh * 4;
#pragma unroll
                for (int q = 0; q < 4; ++q) {
                    float4 v;
                    v.x = fh[q * 4 + 0] + fl[q * 4 + 0] + bop[q * 8 + 0];
                    v.y = fh[q * 4 + 1] + fl[q * 4 + 1] + bop[q * 8 + 1];
                    v.z = fh[q * 4 + 2] + fl[q * 4 + 2] + bop[q * 8 + 2];
                    v.w = fh[q * 4 + 3] + fl[q * 4 + 3] + bop[q * 8 + 3];
                    *(float4*)(op + q * 8) = v;
                }
            }
        }
    }
}

// ---------------- launch ----------------

extern "C" void kernel_launch(void* const* d_in, const int* in_sizes, int n_in,
                              void* d_out, int out_size, void* d_ws, size_t ws_size,
                              hipStream_t stream) {
    const float* z   = (const float*)d_in[0];
    const int*   y   = (const int*)d_in[1];
    const float* W0  = (const float*)d_in[2];
    const float* b0  = (const float*)d_in[3];
    const float* W1  = (const float*)d_in[4];
    const float* b1  = (const float*)d_in[5];
    const float* W2  = (const float*)d_in[6];
    const float* b2  = (const float*)d_in[7];
    const float* W3  = (const float*)d_in[8];
    const float* b3  = (const float*)d_in[9];
    const float* Wu1 = (const float*)d_in[10];
    const float* bu1 = (const float*)d_in[11];
    const float* Wu2 = (const float*)d_in[12];
    const float* bu2 = (const float*)d_in[13];
    const float* Wu3 = (const float*)d_in[14];
    const float* bu3 = (const float*)d_in[15];
    const float* Wo  = (const float*)d_in[16];
    const float* bo  = (const float*)d_in[17];
    float* out = (float*)d_out;

    short* Wp   = (short*)d_ws;                      // 33 * 262144 shorts (16.5 MB)
    short* W0p  = Wp + (size_t)33 * 262144;          // 8192 shorts
    short* WoP  = W0p + 8192;                        // 10 * 32768 shorts
    int* rowidx  = (int*)(WoP + (size_t)10 * 32768); // NB ints
    int* counts  = rowidx + NB;                      // NDOM
    int* cursors = counts + NDOM;                    // NDOM

    hipMemsetAsync(counts, 0, sizeof(int) * 2 * NDOM, stream);
    k_prep<<<1131, 256, 0, stream>>>(W1, W2, W3, Wu1, Wu2, Wu3, W0, Wo, y,
                                     Wp, W0p, WoP, counts);
    k_scatter<<<NB / 256, 256, 0, stream>>>(y, counts, cursors, rowidx);
    k_fused<<<NWIN, 1024, 0, stream>>>(z, rowidx, counts, Wp, W0p, WoP,
                                       b0, b1, b2, b3, bu1, bu2, bu3, bo, out);
}

// Round 13
// 170.673 us; speedup vs baseline: 1.2269x; 1.2269x over previous
//
#include <hip/hip_runtime.h>

#define NB 16384
#define NDOM 10
#define HIDN 512
#define STYLE 64
#define NWIN 512   // NB / 32

typedef short bf16x8 __attribute__((ext_vector_type(8)));
typedef float f32x16 __attribute__((ext_vector_type(16)));

#define MFMA __builtin_amdgcn_mfma_f32_32x32x16_bf16

// ---------------- bf16 helpers ----------------

__device__ __forceinline__ unsigned bfr_hi(float x) {
    unsigned u = __float_as_uint(x);
    return (u + 0x7fffu + ((u >> 16) & 1u)) & 0xffff0000u;  // RNE bf16 in high bits
}

__device__ __forceinline__ unsigned cvtpk(float a, float b) {
    unsigned r;
    asm("v_cvt_pk_bf16_f32 %0, %1, %2" : "=v"(r) : "v"(a), "v"(b));
    return r;   // [15:0]=bf16(a), [31:16]=bf16(b)
}

__device__ __forceinline__ void cvhalf2(const float4& x, const float4& y, uint4& h, uint4& l) {
    float xs[8] = {x.x, x.y, x.z, x.w, y.x, y.y, y.z, y.w};
    unsigned hh[8], ll[8];
#pragma unroll
    for (int i = 0; i < 8; ++i) {
        unsigned hb = bfr_hi(xs[i]);
        hh[i] = hb;
        ll[i] = bfr_hi(xs[i] - __uint_as_float(hb));
    }
    h = make_uint4((hh[0] >> 16) | (hh[1] & 0xffff0000u), (hh[2] >> 16) | (hh[3] & 0xffff0000u),
                   (hh[4] >> 16) | (hh[5] & 0xffff0000u), (hh[6] >> 16) | (hh[7] & 0xffff0000u));
    l = make_uint4((ll[0] >> 16) | (ll[1] & 0xffff0000u), (ll[2] >> 16) | (ll[3] & 0xffff0000u),
                   (ll[4] >> 16) | (ll[5] & 0xffff0000u), (ll[6] >> 16) | (ll[7] & 0xffff0000u));
}

// ---------------- scatter (parallel, 64 blocks) ------
// Placement within a domain is atomic-order dependent, but every row's output
// value is position-independent -> d_out deterministic.

__global__ void k_scatter(const int* __restrict__ y, const int* __restrict__ counts,
                          int* __restrict__ cursors, int* __restrict__ rowidx) {
    __shared__ int soff[NDOM];
    if (threadIdx.x == 0) {
        int s = 0;
        for (int dd = 0; dd < NDOM; ++dd) { soff[dd] = s; s += counts[dd]; }
    }
    __syncthreads();
    int b = blockIdx.x * 256 + threadIdx.x;   // grid 64
    int d = y[b];
    int lane = threadIdx.x & 63;
#pragma unroll
    for (int dd = 0; dd < NDOM; ++dd) {
        unsigned long long bal = __ballot(d == dd);
        if (bal == 0ULL) continue;
        int leader = __builtin_ctzll(bal);
        int base = 0;
        if (d == dd && lane == leader)
            base = atomicAdd(&cursors[dd], (int)__popcll(bal));
        base = __shfl(base, leader);
        if (d == dd) {
            int rank = (int)__popcll(bal & ((1ULL << lane) - 1ULL));
            rowidx[soff[dd] + base + rank] = b;
        }
    }
}

// ---------------- weight prep + histogram (single kernel) ------------------
// Big mats (512x512): per (mat, wq) block of 32768 shorts:
//   addr = ks*1024 + of*512 + k8*256 + c5*8 + j ; k = ks*16+k8*8+j, col = wq*64+of*32+c5
// mats: 0..2 = W1..W3 ; 3+d = Wu1[d] ; 13+d = Wu2[d] ; 23+d = Wu3[d]
// grid: 2112 big-mat (mat, wq, s) + 1 W0 + 10 Wo + 64 hist = 2187

__global__ void k_prep(const float* __restrict__ W1, const float* __restrict__ W2,
                       const float* __restrict__ W3, const float* __restrict__ Wu1,
                       const float* __restrict__ Wu2, const float* __restrict__ Wu3,
                       const float* __restrict__ W0, const float* __restrict__ Wo,
                       const int* __restrict__ y,
                       short* __restrict__ Wp, short* __restrict__ W0p,
                       short* __restrict__ WoP, int* __restrict__ counts)
{
    const int b = blockIdx.x;
    const int t = threadIdx.x;
    if (b < 2112) {
        __shared__ float Ld[64][66];
        const int mat = b >> 6, wq = (b >> 3) & 7, s = b & 7;
        const float* src;
        if (mat < 3) src = (mat == 0 ? W1 : (mat == 1 ? W2 : W3));
        else {
            int g = (mat - 3) / 10, d = (mat - 3) % 10;
            src = (g == 0 ? Wu1 : (g == 1 ? Wu2 : Wu3)) + (size_t)d * HIDN * HIDN;
        }
        short* dst = Wp + (size_t)mat * 262144 + wq * 32768;
        const int r4 = t >> 6, c = t & 63;
#pragma unroll
        for (int p = 0; p < 16; ++p) {
            int k = s * 64 + p * 4 + r4;
            Ld[p * 4 + r4][c] = src[(size_t)k * HIDN + wq * 64 + c];
        }
        __syncthreads();
#pragma unroll
        for (int i = 0; i < 2; ++i) {
            int g = i * 256 + t;
            int ksl = g >> 7, of = (g >> 6) & 1, k8 = (g >> 5) & 1, c5 = g & 31;
            int kk = ksl * 16 + k8 * 8;
            unsigned pk[4];
#pragma unroll
            for (int j2 = 0; j2 < 4; ++j2) {
                unsigned h0 = bfr_hi(Ld[kk + 2 * j2][of * 32 + c5]);
                unsigned h1 = bfr_hi(Ld[kk + 2 * j2 + 1][of * 32 + c5]);
                pk[j2] = (h0 >> 16) | (h1 & 0xffff0000u);
            }
            int ksg = s * 4 + ksl;
            *(uint4*)(dst + ksg * 1024 + of * 512 + k8 * 256 + c5 * 8) =
                make_uint4(pk[0], pk[1], pk[2], pk[3]);
        }
    } else if (b == 2112) {
#pragma unroll
        for (int i = 0; i < 4; ++i) {
            int g = i * 256 + t;   // 1024 granules
            int wq = g >> 7, of = (g >> 6) & 1, k8 = (g >> 5) & 1, c5 = g & 31;
            int col = wq * 64 + of * 32 + c5;
            unsigned pk[4];
#pragma unroll
            for (int j2 = 0; j2 < 4; ++j2) {
                unsigned h0 = bfr_hi(W0[(size_t)(k8 * 8 + 2 * j2) * HIDN + col]);
                unsigned h1 = bfr_hi(W0[(size_t)(k8 * 8 + 2 * j2 + 1) * HIDN + col]);
                pk[j2] = (h0 >> 16) | (h1 & 0xffff0000u);
            }
            *(uint4*)(W0p + g * 8) = make_uint4(pk[0], pk[1], pk[2], pk[3]);
        }
    } else if (b < 2123) {
        const int dom = b - 2113;
        const float* src = Wo + (size_t)dom * HIDN * STYLE;
        short* dst = WoP + (size_t)dom * 32768;
#pragma unroll
        for (int i = 0; i < 16; ++i) {
            int g = i * 256 + t;   // 4096 granules
            int w1 = g >> 11, ks = (g >> 6) & 31, k8 = (g >> 5) & 1, c5 = g & 31;
            int col = w1 * 32 + c5;
            int k0 = ks * 16 + k8 * 8;
            unsigned pk[4];
#pragma unroll
            for (int j2 = 0; j2 < 4; ++j2) {
                unsigned h0 = bfr_hi(src[(size_t)(k0 + 2 * j2) * STYLE + col]);
                unsigned h1 = bfr_hi(src[(size_t)(k0 + 2 * j2 + 1) * STYLE + col]);
                pk[j2] = (h0 >> 16) | (h1 & 0xffff0000u);
            }
            *(uint4*)(dst + g * 8) = make_uint4(pk[0], pk[1], pk[2], pk[3]);
        }
    } else {
        // ---- domain histogram (64 blocks' worth folded in) ----
        int idx = (b - 2123) * 256 + t;
        int d = y[idx];
        int lane = t & 63;
#pragma unroll
        for (int dd = 0; dd < NDOM; ++dd) {
            unsigned long long bal = __ballot(d == dd);
            if (bal != 0ULL && d == dd && lane == __builtin_ctzll(bal))
                atomicAdd(&counts[dd], (int)__popcll(bal));
        }
    }
}

// ---------------- fused persistent kernel ----------------
// 512 blocks x 1024 threads (16 waves), block = 32 sorted rows.
// h is HI-ONLY bf16 in LDS (32.3 KB) -> 2 blocks/CU (wave-capped) =
// 32 waves/CU = 8 waves/SIMD. Per-wave state ~36 VGPR + 16 AGPR -> fits the
// 64-reg budget WITHOUT the round-12 spill (whose cause was the lo-plane
// frags + sL addressing pushing past 64).
// Error budget (measured scaling): 9.5e-7 @ 11 noise terms -> sqrt(15/11)
// ~= 1.15e-6 @ 15 terms, vs 4.08e-6 threshold.
// Wave w (0..15) owns outcols [32w,32w+32). h LDS: octet o=k>>3,
// idx = o*256 + row*8 shorts, 16B/line. Operand-swapped MFMA.
// Weight ring depth 4; h-frags read 1 ks ahead.

__device__ __forceinline__ void pass512(const short* __restrict__ sH,
                                        const short* __restrict__ pW,
                                        int w, int lane, f32x16& acc)
{
#pragma unroll
    for (int e = 0; e < 16; ++e) acc[e] = 0.f;
    const int rb = (lane & 31) * 8;
    const int lh = lane >> 5;
    const short* p = pW + (w >> 1) * 32768 + (w & 1) * 512 + lane * 8;
    // weight ring, depth 4 (4 dwordx4 loads in flight)
    bf16x8 wv[4];
#pragma unroll
    for (int d = 0; d < 4; ++d) wv[d] = *(const bf16x8*)(p + d * 1024);
    // h-frag double buffer (read 1 ks ahead)
    bf16x8 hb[2];
    hb[0] = *(const bf16x8*)(sH + lh * 256 + rb);
#pragma unroll
    for (int ks = 0; ks < 32; ++ks) {
        const int pc = ks & 1, pn = pc ^ 1;
        bf16x8 wk = wv[ks & 3];
        if (ks < 28) wv[ks & 3] = *(const bf16x8*)(p + (ks + 4) * 1024);
        if (ks < 31)
            hb[pn] = *(const bf16x8*)(sH + (2 * (ks + 1) + lh) * 256 + rb);
        acc = MFMA(wk, hb[pc], acc, 0, 0, 0);
    }
}

// epilogue: bias (+ReLU), pack bf16, shuffle-repack so each half-wave writes
// full contiguous 16B lines (conflict-free ds_write_b128).
template<bool RELU>
__device__ __forceinline__ void epi512(short* __restrict__ sH, f32x16& acc,
                                       const float* __restrict__ bias,
                                       int w, int lane, int rlo, int rhi)
{
    const int lh = lane >> 5;
    const int row = lane & 31;
    const bool pred = (row >= rlo && row < rhi);
    unsigned mh[4][2];
#pragma unroll
    for (int q = 0; q < 4; ++q) {
        // my 4 k-values: k = w*32 + q*8 + lh*4 + j
        const float4 bv = *(const float4*)&bias[w * 32 + q * 8 + lh * 4];
        float v[4];
#pragma unroll
        for (int j = 0; j < 4; ++j) {
            float x = acc[q * 4 + j] + (&bv.x)[j];
            if (RELU) x = fmaxf(x, 0.f);
            v[j] = x;
        }
        mh[q][0] = cvtpk(v[0], v[1]);
        mh[q][1] = cvtpk(v[2], v[3]);
    }
    // exchange with lane^32 (same row, other half of each 16B line);
    // lane writes full lines for q = 2t + lh -> contiguous per half-wave
#pragma unroll
    for (int t = 0; t < 2; ++t) {
        const int q = 2 * t + lh;
        const int qs = 2 * t + (lh ^ 1);
        unsigned r0 = (unsigned)__shfl_xor((int)mh[qs][0], 32);
        unsigned r1 = (unsigned)__shfl_xor((int)mh[qs][1], 32);
        uint4 line = lh == 0 ? make_uint4(mh[q][0], mh[q][1], r0, r1)
                             : make_uint4(r0, r1, mh[q][0], mh[q][1]);
        if (pred) *(uint4*)(sH + (w * 4 + q) * 256 + row * 8) = line;
    }
}

__global__ __launch_bounds__(1024, 8)
void k_fused(const float* __restrict__ z, const int* __restrict__ rowidx,
             const int* __restrict__ counts,
             const short* __restrict__ Wp, const short* __restrict__ W0p,
             const short* __restrict__ WoP,
             const float* __restrict__ b0, const float* __restrict__ b1,
             const float* __restrict__ b2, const float* __restrict__ b3,
             const float* __restrict__ bu1, const float* __restrict__ bu2,
             const float* __restrict__ bu3, const float* __restrict__ bo,
             float* __restrict__ out)
{
    __shared__ short sH[16384];   // 32 KiB  (h, hi-only bf16)
    __shared__ int soff[NDOM + 1];

    // XCD-chunked bijective swizzle: neighbors share a domain -> L2 reuse
    const int win = (blockIdx.x & 7) * 64 + (blockIdx.x >> 3);
    const int row0 = win * 32;
    const int tid = threadIdx.x;
    const int lane = tid & 63;
    const int w = tid >> 6;      // 0..15
    const int lh = lane >> 5;

    if (tid == 0) {
        int s = 0;
#pragma unroll
        for (int dd = 0; dd < NDOM; ++dd) { soff[dd] = s; s += counts[dd]; }
        soff[NDOM] = s;
    }
    // soff first read in the head loop — multiple __syncthreads before then

    f32x16 acc;

    // ---- layer 0: z (K=16) -> h (z itself split hi/lo; out hi-only) ----
    {
#pragma unroll
        for (int e = 0; e < 16; ++e) acc[e] = 0.f;
        bf16x8 w0v = *(const bf16x8*)(W0p + (w >> 1) * 1024 + (w & 1) * 512 + lane * 8);
        const int r = lane & 31;
        const int src = rowidx[row0 + r];
        const float* zp = z + (size_t)src * 16 + lh * 8;
        float4 f0 = *(const float4*)zp;
        float4 f1 = *(const float4*)(zp + 4);
        uint4 h, l;
        cvhalf2(f0, f1, h, l);
        bf16x8 zh = *(bf16x8*)&h;
        bf16x8 zl = *(bf16x8*)&l;
        acc = MFMA(w0v, zh, acc, 0, 0, 0);
        acc = MFMA(w0v, zl, acc, 0, 0, 0);
        epi512<true>(sH, acc, b0, w, lane, 0, 32);
        __syncthreads();
    }

    // ---- trunk layers 1-3 ----
#pragma unroll 1
    for (int m = 0; m < 3; ++m) {
        const float* bp = (m == 0) ? b1 : (m == 1) ? b2 : b3;
        pass512(sH, Wp + (size_t)m * 262144, w, lane, acc);
        __syncthreads();
        epi512<true>(sH, acc, bp, w, lane, 0, 32);
        __syncthreads();
    }

    // ---- head layers: per-domain segments (predicated epilogue rows) ----
#pragma unroll 1
    for (int L = 0; L < 3; ++L) {
        const short* WL_ = Wp + (size_t)(3 + L * 10) * 262144;
        const float* bL = (L == 0) ? bu1 : (L == 1) ? bu2 : bu3;
#pragma unroll 1
        for (int d = 0; d < NDOM; ++d) {
            int rlo = soff[d] - row0, rhi = soff[d + 1] - row0;
            rlo = rlo < 0 ? 0 : rlo;
            rhi = rhi > 32 ? 32 : rhi;
            if (rhi <= rlo) continue;
            pass512(sH, WL_ + (size_t)d * 262144, w, lane, acc);
            __syncthreads();
            epi512<true>(sH, acc, bL + d * HIDN, w, lane, rlo, rhi);
            __syncthreads();
        }
    }

    // ---- final 512->64: waves 0-1, wave = 32 outcols; coalesced float4 out ----
    if (w < 2) {
        const int r = lane & 31;
#pragma unroll 1
        for (int d = 0; d < NDOM; ++d) {
            int rlo = soff[d] - row0, rhi = soff[d + 1] - row0;
            rlo = rlo < 0 ? 0 : rlo;
            rhi = rhi > 32 ? 32 : rhi;
            if (rhi <= rlo) continue;
#pragma unroll
            for (int e = 0; e < 16; ++e) acc[e] = 0.f;
            const short* pw = WoP + (size_t)d * 32768 + w * 16384 + lane * 8;
            bf16x8 wb[4];
#pragma unroll
            for (int dd = 0; dd < 4; ++dd) wb[dd] = *(const bf16x8*)(pw + dd * 512);
#pragma unroll
            for (int ks = 0; ks < 32; ++ks) {
                bf16x8 wk = wb[ks & 3];
                if (ks < 28) wb[ks & 3] = *(const bf16x8*)(pw + (ks + 4) * 512);
                bf16x8 bhv = *(const bf16x8*)(sH + (2 * ks + lh) * 256 + (lane & 31) * 8);
                acc = MFMA(wk, bhv, acc, 0, 0, 0);
            }
            if (r >= rlo && r < rhi) {
                const int orow = rowidx[row0 + r];
                float* op = out + (size_t)orow * STYLE + w * 32 + lh * 4;
                const float* bop = bo + d * STYLE + w * 32 + lh * 4;
#pragma unroll
                for (int q = 0; q < 4; ++q) {
                    float4 v;
                    v.x = acc[q * 4 + 0] + bop[q * 8 + 0];
                    v.y = acc[q * 4 + 1] + bop[q * 8 + 1];
                    v.z = acc[q * 4 + 2] + bop[q * 8 + 2];
                    v.w = acc[q * 4 + 3] + bop[q * 8 + 3];
                    *(float4*)(op + q * 8) = v;
                }
            }
        }
    }
}

// ---------------- launch ----------------

extern "C" void kernel_launch(void* const* d_in, const int* in_sizes, int n_in,
                              void* d_out, int out_size, void* d_ws, size_t ws_size,
                              hipStream_t stream) {
    const float* z   = (const float*)d_in[0];
    const int*   y   = (const int*)d_in[1];
    const float* W0  = (const float*)d_in[2];
    const float* b0  = (const float*)d_in[3];
    const float* W1  = (const float*)d_in[4];
    const float* b1  = (const float*)d_in[5];
    const float* W2  = (const float*)d_in[6];
    const float* b2  = (const float*)d_in[7];
    const float* W3  = (const float*)d_in[8];
    const float* b3  = (const float*)d_in[9];
    const float* Wu1 = (const float*)d_in[10];
    const float* bu1 = (const float*)d_in[11];
    const float* Wu2 = (const float*)d_in[12];
    const float* bu2 = (const float*)d_in[13];
    const float* Wu3 = (const float*)d_in[14];
    const float* bu3 = (const float*)d_in[15];
    const float* Wo  = (const float*)d_in[16];
    const float* bo  = (const float*)d_in[17];
    float* out = (float*)d_out;

    short* Wp   = (short*)d_ws;                      // 33 * 262144 shorts (16.5 MB)
    short* W0p  = Wp + (size_t)33 * 262144;          // 8192 shorts
    short* WoP  = W0p + 8192;                        // 10 * 32768 shorts
    int* rowidx  = (int*)(WoP + (size_t)10 * 32768); // NB ints
    int* counts  = rowidx + NB;                      // NDOM
    int* cursors = counts + NDOM;                    // NDOM

    hipMemsetAsync(counts, 0, sizeof(int) * 2 * NDOM, stream);
    k_prep<<<2187, 256, 0, stream>>>(W1, W2, W3, Wu1, Wu2, Wu3, W0, Wo, y,
                                     Wp, W0p, WoP, counts);
    k_scatter<<<NB / 256, 256, 0, stream>>>(y, counts, cursors, rowidx);
    k_fused<<<NWIN, 1024, 0, stream>>>(z, rowidx, counts, Wp, W0p, WoP,
                                       b0, b1, b2, b3, bu1, bu2, bu3, bo, out);
}

// Round 14
// 162.681 us; speedup vs baseline: 1.2872x; 1.0491x over previous
//
#include <hip/hip_runtime.h>

#define NB 16384
#define NDOM 10
#define HIDN 512
#define STYLE 64
#define NWIN 256   // NB / 64

typedef short bf16x8 __attribute__((ext_vector_type(8)));
typedef float f32x16 __attribute__((ext_vector_type(16)));

#define MFMA __builtin_amdgcn_mfma_f32_32x32x16_bf16

// ---------------- bf16 helpers ----------------

__device__ __forceinline__ unsigned bfr_hi(float x) {
    unsigned u = __float_as_uint(x);
    return (u + 0x7fffu + ((u >> 16) & 1u)) & 0xffff0000u;  // RNE bf16 in high bits
}

__device__ __forceinline__ unsigned cvtpk(float a, float b) {
    unsigned r;
    asm("v_cvt_pk_bf16_f32 %0, %1, %2" : "=v"(r) : "v"(a), "v"(b));
    return r;   // [15:0]=bf16(a), [31:16]=bf16(b)
}

__device__ __forceinline__ void cvhalf2(const float4& x, const float4& y, uint4& h, uint4& l) {
    float xs[8] = {x.x, x.y, x.z, x.w, y.x, y.y, y.z, y.w};
    unsigned hh[8], ll[8];
#pragma unroll
    for (int i = 0; i < 8; ++i) {
        unsigned hb = bfr_hi(xs[i]);
        hh[i] = hb;
        ll[i] = bfr_hi(xs[i] - __uint_as_float(hb));
    }
    h = make_uint4((hh[0] >> 16) | (hh[1] & 0xffff0000u), (hh[2] >> 16) | (hh[3] & 0xffff0000u),
                   (hh[4] >> 16) | (hh[5] & 0xffff0000u), (hh[6] >> 16) | (hh[7] & 0xffff0000u));
    l = make_uint4((ll[0] >> 16) | (ll[1] & 0xffff0000u), (ll[2] >> 16) | (ll[3] & 0xffff0000u),
                   (ll[4] >> 16) | (ll[5] & 0xffff0000u), (ll[6] >> 16) | (ll[7] & 0xffff0000u));
}

// ---------------- scatter (parallel, 64 blocks) ------
// Placement within a domain is atomic-order dependent, but every row's output
// value is position-independent -> d_out deterministic.

__global__ void k_scatter(const int* __restrict__ y, const int* __restrict__ counts,
                          int* __restrict__ cursors, int* __restrict__ rowidx) {
    __shared__ int soff[NDOM];
    if (threadIdx.x == 0) {
        int s = 0;
        for (int dd = 0; dd < NDOM; ++dd) { soff[dd] = s; s += counts[dd]; }
    }
    __syncthreads();
    int b = blockIdx.x * 256 + threadIdx.x;   // grid 64
    int d = y[b];
    int lane = threadIdx.x & 63;
#pragma unroll
    for (int dd = 0; dd < NDOM; ++dd) {
        unsigned long long bal = __ballot(d == dd);
        if (bal == 0ULL) continue;
        int leader = __builtin_ctzll(bal);
        int base = 0;
        if (d == dd && lane == leader)
            base = atomicAdd(&cursors[dd], (int)__popcll(bal));
        base = __shfl(base, leader);
        if (d == dd) {
            int rank = (int)__popcll(bal & ((1ULL << lane) - 1ULL));
            rowidx[soff[dd] + base + rank] = b;
        }
    }
}

// ---------------- weight prep + histogram (single kernel) ------------------
// Big mats (512x512): per (mat, wq) block of 32768 shorts:
//   addr = ks*1024 + of*512 + k8*256 + c5*8 + j ; k = ks*16+k8*8+j, col = wq*64+of*32+c5
// mats: 0..2 = W1..W3 ; 3+d = Wu1[d] ; 13+d = Wu2[d] ; 23+d = Wu3[d]
// grid: 2112 big-mat (mat, wq, s) + 1 W0 + 10 Wo + 64 hist = 2187

__global__ void k_prep(const float* __restrict__ W1, const float* __restrict__ W2,
                       const float* __restrict__ W3, const float* __restrict__ Wu1,
                       const float* __restrict__ Wu2, const float* __restrict__ Wu3,
                       const float* __restrict__ W0, const float* __restrict__ Wo,
                       const int* __restrict__ y,
                       short* __restrict__ Wp, short* __restrict__ W0p,
                       short* __restrict__ WoP, int* __restrict__ counts)
{
    const int b = blockIdx.x;
    const int t = threadIdx.x;
    if (b < 2112) {
        __shared__ float Ld[64][68];   // rows 272B (16B-aligned) for float4 stores
        const int mat = b >> 6, wq = (b >> 3) & 7, s = b & 7;
        const float* src;
        if (mat < 3) src = (mat == 0 ? W1 : (mat == 1 ? W2 : W3));
        else {
            int g = (mat - 3) / 10, d = (mat - 3) % 10;
            src = (g == 0 ? Wu1 : (g == 1 ? Wu2 : Wu3)) + (size_t)d * HIDN * HIDN;
        }
        short* dst = Wp + (size_t)mat * 262144 + wq * 32768;
        // 64x64 f32 tile, float4-vectorized loads (4 loads/thread)
#pragma unroll
        for (int i = 0; i < 4; ++i) {
            int idx = i * 256 + t;         // 1024 float4 granules
            int row = idx >> 4, c4 = idx & 15;
            *(float4*)&Ld[row][c4 * 4] =
                *(const float4*)(src + (size_t)(s * 64 + row) * HIDN + wq * 64 + c4 * 4);
        }
        __syncthreads();
#pragma unroll
        for (int i = 0; i < 2; ++i) {
            int g = i * 256 + t;
            int ksl = g >> 7, of = (g >> 6) & 1, k8 = (g >> 5) & 1, c5 = g & 31;
            int kk = ksl * 16 + k8 * 8;
            unsigned pk[4];
#pragma unroll
            for (int j2 = 0; j2 < 4; ++j2) {
                unsigned h0 = bfr_hi(Ld[kk + 2 * j2][of * 32 + c5]);
                unsigned h1 = bfr_hi(Ld[kk + 2 * j2 + 1][of * 32 + c5]);
                pk[j2] = (h0 >> 16) | (h1 & 0xffff0000u);
            }
            int ksg = s * 4 + ksl;
            *(uint4*)(dst + ksg * 1024 + of * 512 + k8 * 256 + c5 * 8) =
                make_uint4(pk[0], pk[1], pk[2], pk[3]);
        }
    } else if (b == 2112) {
#pragma unroll
        for (int i = 0; i < 4; ++i) {
            int g = i * 256 + t;   // 1024 granules
            int wq = g >> 7, of = (g >> 6) & 1, k8 = (g >> 5) & 1, c5 = g & 31;
            int col = wq * 64 + of * 32 + c5;
            unsigned pk[4];
#pragma unroll
            for (int j2 = 0; j2 < 4; ++j2) {
                unsigned h0 = bfr_hi(W0[(size_t)(k8 * 8 + 2 * j2) * HIDN + col]);
                unsigned h1 = bfr_hi(W0[(size_t)(k8 * 8 + 2 * j2 + 1) * HIDN + col]);
                pk[j2] = (h0 >> 16) | (h1 & 0xffff0000u);
            }
            *(uint4*)(W0p + g * 8) = make_uint4(pk[0], pk[1], pk[2], pk[3]);
        }
    } else if (b < 2123) {
        const int dom = b - 2113;
        const float* src = Wo + (size_t)dom * HIDN * STYLE;
        short* dst = WoP + (size_t)dom * 32768;
#pragma unroll
        for (int i = 0; i < 16; ++i) {
            int g = i * 256 + t;   // 4096 granules
            int w1 = g >> 11, ks = (g >> 6) & 31, k8 = (g >> 5) & 1, c5 = g & 31;
            int col = w1 * 32 + c5;
            int k0 = ks * 16 + k8 * 8;
            unsigned pk[4];
#pragma unroll
            for (int j2 = 0; j2 < 4; ++j2) {
                unsigned h0 = bfr_hi(src[(size_t)(k0 + 2 * j2) * STYLE + col]);
                unsigned h1 = bfr_hi(src[(size_t)(k0 + 2 * j2 + 1) * STYLE + col]);
                pk[j2] = (h0 >> 16) | (h1 & 0xffff0000u);
            }
            *(uint4*)(dst + g * 8) = make_uint4(pk[0], pk[1], pk[2], pk[3]);
        }
    } else {
        // ---- domain histogram (64 blocks' worth folded in) ----
        int idx = (b - 2123) * 256 + t;
        int d = y[idx];
        int lane = t & 63;
#pragma unroll
        for (int dd = 0; dd < NDOM; ++dd) {
            unsigned long long bal = __ballot(d == dd);
            if (bal != 0ULL && d == dd && lane == __builtin_ctzll(bal))
                atomicAdd(&counts[dd], (int)__popcll(bal));
        }
    }
}

// ---------------- fused persistent kernel ----------------
// 256 blocks x 1024 threads (16 waves), block = 64 sorted rows; 64.1 KB LDS,
// 1 block/CU, 4 waves/SIMD (launch_bounds(1024,4): 128-reg budget).
// KEY: 64 rows/block halves the per-CU weight-INSTRUCTION count vs round 13
// (each weight b128 feeds 2 MFMAs via nf=2) — round 13 showed the kernel is
// vector-memory-instruction-issue bound (both ports <50%, issue util 47%).
// Wave w (0..15) owns outcols [32w,32w+32); rows = nf*32 + (lane&31).
// h LDS (hi-only bf16): octet o=k>>3, idx = o*512 + row*8 shorts, 16B/line.
// Operand-swapped MFMA: A = weights (m=outcol), B = activations (n=batchrow).
// Weight ring depth 4; h-frags read 1 ks ahead. Regs ~95: acc 32 + ring 16 +
// hb 32 + addr — no spill (round-12 lesson: watch WRITE_SIZE).

template<int NFM>
__device__ __forceinline__ void pass512(const short* __restrict__ sH,
                                        const short* __restrict__ pW,
                                        int w, int lane, f32x16 acc[2])
{
#pragma unroll
    for (int nf = 0; nf < 2; ++nf)
        if (NFM & (1 << nf))
#pragma unroll
            for (int e = 0; e < 16; ++e) acc[nf][e] = 0.f;
    const int rb = (lane & 31) * 8;
    const int lh = lane >> 5;
    const short* p = pW + (w >> 1) * 32768 + (w & 1) * 512 + lane * 8;
    // weight ring, depth 4 (4 dwordx4 loads in flight)
    bf16x8 wv[4];
#pragma unroll
    for (int d = 0; d < 4; ++d) wv[d] = *(const bf16x8*)(p + d * 1024);
    // h-frag double buffer (read 1 ks ahead)
    bf16x8 hb[2][2];
    const int base0 = lh * 512 + rb;
#pragma unroll
    for (int nf = 0; nf < 2; ++nf)
        if (NFM & (1 << nf)) hb[0][nf] = *(const bf16x8*)(sH + base0 + nf * 256);
#pragma unroll
    for (int ks = 0; ks < 32; ++ks) {
        const int pc = ks & 1, pn = pc ^ 1;
        bf16x8 wk = wv[ks & 3];
        if (ks < 28) wv[ks & 3] = *(const bf16x8*)(p + (ks + 4) * 1024);
        if (ks < 31) {
            const int basen = (2 * (ks + 1) + lh) * 512 + rb;
#pragma unroll
            for (int nf = 0; nf < 2; ++nf)
                if (NFM & (1 << nf)) hb[pn][nf] = *(const bf16x8*)(sH + basen + nf * 256);
        }
#pragma unroll
        for (int nf = 0; nf < 2; ++nf)
            if (NFM & (1 << nf)) acc[nf] = MFMA(wk, hb[pc][nf], acc[nf], 0, 0, 0);
    }
}

// epilogue: bias (+ReLU), pack bf16, shuffle-repack so each half-wave writes
// full contiguous 16B lines (conflict-free ds_write_b128).
template<int NFM, bool RELU>
__device__ __forceinline__ void epi512(short* __restrict__ sH, f32x16 acc[2],
                                       const float* __restrict__ bias,
                                       int w, int lane, int rlo, int rhi)
{
    const int lh = lane >> 5;
#pragma unroll
    for (int nf = 0; nf < 2; ++nf) {
        if (!(NFM & (1 << nf))) continue;
        const int row = nf * 32 + (lane & 31);
        const bool pred = (row >= rlo && row < rhi);
        unsigned mh[4][2];
#pragma unroll
        for (int q = 0; q < 4; ++q) {
            // my 4 k-values: k = w*32 + q*8 + lh*4 + j
            const float4 bv = *(const float4*)&bias[w * 32 + q * 8 + lh * 4];
            float v[4];
#pragma unroll
            for (int j = 0; j < 4; ++j) {
                float x = acc[nf][q * 4 + j] + (&bv.x)[j];
                if (RELU) x = fmaxf(x, 0.f);
                v[j] = x;
            }
            mh[q][0] = cvtpk(v[0], v[1]);
            mh[q][1] = cvtpk(v[2], v[3]);
        }
        // exchange with lane^32 (same row, other k-half of each 16B line)
#pragma unroll
        for (int t = 0; t < 2; ++t) {
            const int q = 2 * t + lh;
            const int qs = 2 * t + (lh ^ 1);
            unsigned r0 = (unsigned)__shfl_xor((int)mh[qs][0], 32);
            unsigned r1 = (unsigned)__shfl_xor((int)mh[qs][1], 32);
            uint4 line = lh == 0 ? make_uint4(mh[q][0], mh[q][1], r0, r1)
                                 : make_uint4(r0, r1, mh[q][0], mh[q][1]);
            if (pred) *(uint4*)(sH + (w * 4 + q) * 512 + row * 8) = line;
        }
    }
}

__global__ __launch_bounds__(1024, 4)
void k_fused(const float* __restrict__ z, const int* __restrict__ rowidx,
             const int* __restrict__ counts,
             const short* __restrict__ Wp, const short* __restrict__ W0p,
             const short* __restrict__ WoP,
             const float* __restrict__ b0, const float* __restrict__ b1,
             const float* __restrict__ b2, const float* __restrict__ b3,
             const float* __restrict__ bu1, const float* __restrict__ bu2,
             const float* __restrict__ bu3, const float* __restrict__ bo,
             float* __restrict__ out)
{
    __shared__ short sH[32768];   // 64 KiB (h, hi-only bf16, 64 rows)
    __shared__ int soff[NDOM + 1];

    // XCD-chunked bijective swizzle: neighbors share a domain -> L2 reuse
    const int win = (blockIdx.x & 7) * 32 + (blockIdx.x >> 3);
    const int row0 = win * 64;
    const int tid = threadIdx.x;
    const int lane = tid & 63;
    const int w = tid >> 6;      // 0..15
    const int lh = lane >> 5;

    if (tid == 0) {
        int s = 0;
#pragma unroll
        for (int dd = 0; dd < NDOM; ++dd) { soff[dd] = s; s += counts[dd]; }
        soff[NDOM] = s;
    }
    // soff first read in the head loop — multiple __syncthreads before then

    f32x16 acc[2];

    // ---- layer 0: z (K=16) -> h (z itself split hi/lo; out hi-only) ----
    {
        bf16x8 w0v = *(const bf16x8*)(W0p + (w >> 1) * 1024 + (w & 1) * 512 + lane * 8);
#pragma unroll
        for (int nf = 0; nf < 2; ++nf) {
#pragma unroll
            for (int e = 0; e < 16; ++e) acc[nf][e] = 0.f;
            const int r = nf * 32 + (lane & 31);
            const int src = rowidx[row0 + r];
            const float* zp = z + (size_t)src * 16 + lh * 8;
            float4 f0 = *(const float4*)zp;
            float4 f1 = *(const float4*)(zp + 4);
            uint4 h, l;
            cvhalf2(f0, f1, h, l);
            bf16x8 zh = *(bf16x8*)&h;
            bf16x8 zl = *(bf16x8*)&l;
            acc[nf] = MFMA(w0v, zh, acc[nf], 0, 0, 0);
            acc[nf] = MFMA(w0v, zl, acc[nf], 0, 0, 0);
        }
        epi512<3, true>(sH, acc, b0, w, lane, 0, 64);
        __syncthreads();
    }

    // ---- trunk layers 1-3 ----
#pragma unroll 1
    for (int m = 0; m < 3; ++m) {
        const float* bp = (m == 0) ? b1 : (m == 1) ? b2 : b3;
        pass512<3>(sH, Wp + (size_t)m * 262144, w, lane, acc);
        __syncthreads();
        epi512<3, true>(sH, acc, bp, w, lane, 0, 64);
        __syncthreads();
    }

    // ---- head layers: per-domain, nf-granular (32-row groups) ----
#pragma unroll 1
    for (int L = 0; L < 3; ++L) {
        const short* WL_ = Wp + (size_t)(3 + L * 10) * 262144;
        const float* bL = (L == 0) ? bu1 : (L == 1) ? bu2 : bu3;
#pragma unroll 1
        for (int d = 0; d < NDOM; ++d) {
            int rlo = soff[d] - row0, rhi = soff[d + 1] - row0;
            rlo = rlo < 0 ? 0 : rlo;
            rhi = rhi > 64 ? 64 : rhi;
            if (rhi <= rlo) continue;
            const int nfm = (rlo < 32 ? 1 : 0) | (rhi > 32 ? 2 : 0);
            const short* pw = WL_ + (size_t)d * 262144;
            if (nfm == 3)      pass512<3>(sH, pw, w, lane, acc);
            else if (nfm == 1) pass512<1>(sH, pw, w, lane, acc);
            else               pass512<2>(sH, pw, w, lane, acc);
            __syncthreads();
            if (nfm == 3)      epi512<3, true>(sH, acc, bL + d * HIDN, w, lane, rlo, rhi);
            else if (nfm == 1) epi512<1, true>(sH, acc, bL + d * HIDN, w, lane, rlo, rhi);
            else               epi512<2, true>(sH, acc, bL + d * HIDN, w, lane, rlo, rhi);
            __syncthreads();
        }
    }

    // ---- final 512->64: 4 waves, wave = (row-half, col-half) tile ----
    if (w < 4) {
        const int rh = w >> 1, ch = w & 1;
        const int r = rh * 32 + (lane & 31);
#pragma unroll 1
        for (int d = 0; d < NDOM; ++d) {
            int rlo = soff[d] - row0, rhi = soff[d + 1] - row0;
            rlo = rlo < 0 ? 0 : rlo;
            rhi = rhi > 64 ? 64 : rhi;
            if (rhi <= rlo) continue;
            if (rhi <= rh * 32 || rlo >= rh * 32 + 32) continue;
            f32x16 fa;
#pragma unroll
            for (int e = 0; e < 16; ++e) fa[e] = 0.f;
            const short* pw = WoP + (size_t)d * 32768 + ch * 16384 + lane * 8;
            bf16x8 wb[4];
#pragma unroll
            for (int dd = 0; dd < 4; ++dd) wb[dd] = *(const bf16x8*)(pw + dd * 512);
            const int hbase = (rh * 32 + (lane & 31)) * 8;
#pragma unroll
            for (int ks = 0; ks < 32; ++ks) {
                bf16x8 wk = wb[ks & 3];
                if (ks < 28) wb[ks & 3] = *(const bf16x8*)(pw + (ks + 4) * 512);
                bf16x8 bhv = *(const bf16x8*)(sH + (2 * ks + lh) * 512 + hbase);
                fa = MFMA(wk, bhv, fa, 0, 0, 0);
            }
            if (r >= rlo && r < rhi) {
                const int orow = rowidx[row0 + r];
                float* op = out + (size_t)orow * STYLE + ch * 32 + lh * 4;
                const float* bop = bo + d * STYLE + ch * 32 + lh * 4;
#pragma unroll
                for (int q = 0; q < 4; ++q) {
                    float4 v;
                    v.x = fa[q * 4 + 0] + bop[q * 8 + 0];
                    v.y = fa[q * 4 + 1] + bop[q * 8 + 1];
                    v.z = fa[q * 4 + 2] + bop[q * 8 + 2];
                    v.w = fa[q * 4 + 3] + bop[q * 8 + 3];
                    *(float4*)(op + q * 8) = v;
                }
            }
        }
    }
}

// ---------------- launch ----------------

extern "C" void kernel_launch(void* const* d_in, const int* in_sizes, int n_in,
                              void* d_out, int out_size, void* d_ws, size_t ws_size,
                              hipStream_t stream) {
    const float* z   = (const float*)d_in[0];
    const int*   y   = (const int*)d_in[1];
    const float* W0  = (const float*)d_in[2];
    const float* b0  = (const float*)d_in[3];
    const float* W1  = (const float*)d_in[4];
    const float* b1  = (const float*)d_in[5];
    const float* W2  = (const float*)d_in[6];
    const float* b2  = (const float*)d_in[7];
    const float* W3  = (const float*)d_in[8];
    const float* b3  = (const float*)d_in[9];
    const float* Wu1 = (const float*)d_in[10];
    const float* bu1 = (const float*)d_in[11];
    const float* Wu2 = (const float*)d_in[12];
    const float* bu2 = (const float*)d_in[13];
    const float* Wu3 = (const float*)d_in[14];
    const float* bu3 = (const float*)d_in[15];
    const float* Wo  = (const float*)d_in[16];
    const float* bo  = (const float*)d_in[17];
    float* out = (float*)d_out;

    short* Wp   = (short*)d_ws;                      // 33 * 262144 shorts (16.5 MB)
    short* W0p  = Wp + (size_t)33 * 262144;          // 8192 shorts
    short* WoP  = W0p + 8192;                        // 10 * 32768 shorts
    int* rowidx  = (int*)(WoP + (size_t)10 * 32768); // NB ints
    int* counts  = rowidx + NB;                      // NDOM
    int* cursors = counts + NDOM;                    // NDOM

    hipMemsetAsync(counts, 0, sizeof(int) * 2 * NDOM, stream);
    k_prep<<<2187, 256, 0, stream>>>(W1, W2, W3, Wu1, Wu2, Wu3, W0, Wo, y,
                                     Wp, W0p, WoP, counts);
    k_scatter<<<NB / 256, 256, 0, stream>>>(y, counts, cursors, rowidx);
    k_fused<<<NWIN, 1024, 0, stream>>>(z, rowidx, counts, Wp, W0p, WoP,
                                       b0, b1, b2, b3, bu1, bu2, bu3, bo, out);
}